// Round 7
// baseline (244.437 us; speedup 1.0000x reference)
//
#include <hip/hip_runtime.h>
#include <hip/hip_cooperative_groups.h>
#include <hip/hip_bf16.h>
#include <cstdint>

namespace cg = cooperative_groups;

#define NQ 256
#define NK 2048
#define BB 2
#define SCALE 0.17677669529663687f  // 32^-0.5

// ws byte offsets (16B aligned)
#define TB_OFF 0u         // f16[64000]   tables [i][z][y][x][h]          128000 B
#define QP_OFF 128000u    // float[131072]  q-proj (B,nQ,256), pre-scaled 524288 B
#define KT_OFF 652288u    // float[131072]  k-proj transposed (B,32,nK)   524288 B
#define VP_OFF 1176576u   // float[131072]  v-proj (B,nK,32)              524288 B

typedef unsigned short u16;
typedef _Float16 h16;
union U16x8 { uint4 u; h16 h[8]; };

struct Axis { int o0, o1; float w0, w1; };

static __device__ __forceinline__ Axis axis_setup(float dv, int stride) {
  float g = copysignf(__log2f(fmaf(fabsf(dv), 512.f, 1.f)) * (1.f / 12.f), dv);
  float p = fmaf(g, 4.5f, 4.5f);
  float f = floorf(p);
  int i0 = (int)f;
  float w1v = p - f;
  float w0v = 1.f - w1v;
  Axis a;
  a.w0 = ((unsigned)i0 <= 9u) ? w0v : 0.f;
  a.w1 = ((unsigned)(i0 + 1) <= 9u) ? w1v : 0.f;
  int c0 = min(max(i0, 0), 9);
  int c1 = min(max(i0 + 1, 0), 9);
  a.o0 = c0 * stride;
  a.o1 = c1 * stride;
  return a;
}

#define DO_CORNER(CU, W, J) do { float ww = (W); \
  acc[0][J] = fmaf((float)(CU).h[0], ww, acc[0][J]); \
  acc[1][J] = fmaf((float)(CU).h[1], ww, acc[1][J]); \
  acc[2][J] = fmaf((float)(CU).h[2], ww, acc[2][J]); \
  acc[3][J] = fmaf((float)(CU).h[3], ww, acc[3][J]); \
  acc[4][J] = fmaf((float)(CU).h[4], ww, acc[4][J]); \
  acc[5][J] = fmaf((float)(CU).h[5], ww, acc[5][J]); \
  acc[6][J] = fmaf((float)(CU).h[6], ww, acc[6][J]); \
  acc[7][J] = fmaf((float)(CU).h[7], ww, acc[7][J]); } while (0)

__global__ __launch_bounds__(1024, 4) void k_all(
    const float* __restrict__ query, const float* __restrict__ key,
    const float* __restrict__ qw,    const float* __restrict__ qb,
    const float* __restrict__ kw,    const float* __restrict__ kb,
    const float* __restrict__ vw,    const float* __restrict__ vb,
    const float* __restrict__ w1g,   const float* __restrict__ b1g,
    const float* __restrict__ w2g,
    const float* __restrict__ xyz,   const float* __restrict__ refp,
    const float* __restrict__ pw,    const float* __restrict__ pb,
    u16* __restrict__ tbw,   float* __restrict__ qp,
    float* __restrict__ kpT, float* __restrict__ vp,
    float* __restrict__ attn, float* __restrict__ out) {
  // un: prep = role scratch; mega phase 1-2 = f16 tables (125 KB); phase 4 = p f32 (128 KB)
  __shared__ __align__(16) char un[131072];
  __shared__ __align__(16) float red4[2][8][8][32];  // 16 KB
  __shared__ __align__(16) float qrow[2][256];
  __shared__ __align__(16) float rp[2][24];
  __shared__ __align__(16) float red[2][64];

  int bid = blockIdx.x, t = threadIdx.x;

  // ================= PREP PHASE =================
  if (bid < 128) {
    // ---- kv-proj: 32 same-b rows; kw,vw staged in LDS ----
    float* rows = (float*)un;            // [32][256]  32 KB
    float* kwl  = rows + 8192;           // [256][32]  32 KB
    float* vwl  = kwl + 8192;            // [256][32]  32 KB
    int b = bid >> 6, k0b = (bid & 63) * 32;
    for (int i = t; i < 2048; i += 1024) {
      int rr = i >> 6, c4 = i & 63;
      ((float4*)rows)[i] = ((const float4*)key)[((k0b + rr) * 2 + b) * 64 + c4];
    }
    for (int i = t; i < 2048; i += 1024) ((float4*)kwl)[i] = ((const float4*)kw)[i];
    for (int i = t; i < 2048; i += 1024) ((float4*)vwl)[i] = ((const float4*)vw)[i];
    __syncthreads();
    int ks = t >> 5, d = t & 31;
    float a = kb[d], av = vb[d];
    const float* rw = rows + ks * 256;
    #pragma unroll 4
    for (int m = 0; m < 256; ++m) {
      float rv = rw[m];
      a  = fmaf(rv, kwl[m * 32 + d], a);
      av = fmaf(rv, vwl[m * 32 + d], av);
    }
    int k = k0b + ks;
    vp[(b * NK + k) * 32 + d] = av;
    __syncthreads();
    float* f1 = (float*)un;              // [32][33] transpose pad
    f1[d * 33 + ks] = a;
    __syncthreads();
    int dd = t >> 5, kk = t & 31;
    kpT[(b * 32 + dd) * NK + k0b + kk] = f1[dd * 33 + kk];
  } else if (bid < 192) {
    // ---- q-proj (pre-scaled): 8 rows per block, 2 cols/thread ----
    float* rows = (float*)un;            // [8][256] 8 KB
    int qg = bid - 128;
    for (int i = t; i < 512; i += 1024) {
      int rr = i >> 6, c4 = i & 63;
      int g = qg * 8 + rr, bq = g >> 8, q = g & 255;
      ((float4*)rows)[i] = ((const float4*)query)[(q * BB + bq) * 64 + c4];
    }
    __syncthreads();
    int r = t >> 7, c0 = (t & 127) * 2;
    int g = qg * 8 + r;
    const float* rw = rows + r * 256;
    float2 acc2 = *(const float2*)&qb[c0];
    #pragma unroll 4
    for (int m = 0; m < 256; ++m) {
      float rv = rw[m];
      float2 w2v = *(const float2*)&qw[m * 256 + c0];
      acc2.x = fmaf(rv, w2v.x, acc2.x);
      acc2.y = fmaf(rv, w2v.y, acc2.y);
    }
    float2 o; o.x = acc2.x * SCALE; o.y = acc2.y * SCALE;
    *(float2*)&qp[g * 256 + c0] = o;
  } else if (bid < 200) {
    // ---- cpb tables (f16): one i per block, 1000 cells ----
    float* w1 = (float*)un;              // 384
    float* b1 = w1 + 384;                // 128
    float* w2 = b1 + 128;                // 1024
    int i = bid - 192;
    if (t < 384) w1[t] = w1g[i * 384 + t];
    else if (t < 512) b1[t - 384] = b1g[i * 128 + (t - 384)];
    if (t < 1024) w2[t] = w2g[i * 1024 + t];
    __syncthreads();
    if (t < 1000) {
      int cell = t;
      int z = cell / 100, y = (cell / 10) % 10, x = cell % 10;
      const float step = 8.0f / 9.0f;
      float cz = -4.f + z * step, cy = -4.f + y * step, cx = -4.f + x * step;
      float o0 = 0, o1 = 0, o2 = 0, o3 = 0, o4 = 0, o5 = 0, o6 = 0, o7 = 0;
      for (int d = 0; d < 128; ++d) {
        float h = fmaxf(fmaf(cz, w1[d], fmaf(cy, w1[128 + d], fmaf(cx, w1[256 + d], b1[d]))), 0.f);
        const float* w2r = &w2[d * 8];
        o0 = fmaf(h, w2r[0], o0); o1 = fmaf(h, w2r[1], o1);
        o2 = fmaf(h, w2r[2], o2); o3 = fmaf(h, w2r[3], o3);
        o4 = fmaf(h, w2r[4], o4); o5 = fmaf(h, w2r[5], o5);
        o6 = fmaf(h, w2r[6], o6); o7 = fmaf(h, w2r[7], o7);
      }
      U16x8 R;
      R.h[0] = (h16)o0; R.h[1] = (h16)o1; R.h[2] = (h16)o2; R.h[3] = (h16)o3;
      R.h[4] = (h16)o4; R.h[5] = (h16)o5; R.h[6] = (h16)o6; R.h[7] = (h16)o7;
      *(uint4*)&tbw[i * 8000 + cell * 8] = R.u;
    }
  }

  cg::this_grid().sync();

  // ================= MEGA PHASE =================
  u16* tb = (u16*)un;
  float* p = (float*)un;
  int b = bid >> 7, qc = bid & 127;

  for (int idx = t; idx < 8000; idx += 1024)
    ((uint4*)tb)[idx] = ((const uint4*)tbw)[idx];
  if (t < 128) {
    int qh2 = t >> 6, c = t & 63;
    ((float4*)qrow[qh2])[c] = ((const float4*)(qp + (b * 256 + qc * 2 + qh2) * 256))[c];
  } else if (t < 140) {
    int idx = t - 128;
    int qh2 = idx / 6, c = idx % 6;
    ((float4*)rp[qh2])[c] = ((const float4*)(refp + (b * 256 + qc * 2 + qh2) * 24))[c];
  }
  __syncthreads();

  int wv = t >> 6, l = t & 63;
  int qh = wv >> 3, wvl = wv & 7;
  int q = qc * 2 + qh;
  int k0 = wvl * 256 + l * 4;
  float acc[8][4] = {};

  // phase 1: qk^T
  const float* kT = kpT + b * (32 * NK);
  #pragma unroll 2
  for (int dq = 0; dq < 8; ++dq) {
    const float* kp0 = kT + (dq * 4) * NK + k0;
    float4 kv0 = *(const float4*)(kp0);
    float4 kv1 = *(const float4*)(kp0 + NK);
    float4 kv2 = *(const float4*)(kp0 + 2 * NK);
    float4 kv3 = *(const float4*)(kp0 + 3 * NK);
    #pragma unroll
    for (int h = 0; h < 8; ++h) {
      float4 qv = *(const float4*)&qrow[qh][h * 32 + dq * 4];
      acc[h][0] = fmaf(qv.x, kv0.x, fmaf(qv.y, kv1.x, fmaf(qv.z, kv2.x, fmaf(qv.w, kv3.x, acc[h][0]))));
      acc[h][1] = fmaf(qv.x, kv0.y, fmaf(qv.y, kv1.y, fmaf(qv.z, kv2.y, fmaf(qv.w, kv3.y, acc[h][1]))));
      acc[h][2] = fmaf(qv.x, kv0.z, fmaf(qv.y, kv1.z, fmaf(qv.z, kv2.z, fmaf(qv.w, kv3.z, acc[h][2]))));
      acc[h][3] = fmaf(qv.x, kv0.w, fmaf(qv.y, kv1.w, fmaf(qv.z, kv2.w, fmaf(qv.w, kv3.w, acc[h][3]))));
    }
  }

  // phase 2: rpe trilinear sampling
  {
    const float* xp = xyz + (size_t)(b * NK + k0) * 3;
    float4 X0 = *(const float4*)(xp);
    float4 X1 = *(const float4*)(xp + 4);
    float4 X2 = *(const float4*)(xp + 8);
    float xv[4] = { X0.x, X0.w, X1.z, X2.y };
    float yv[4] = { X0.y, X1.x, X1.w, X2.z };
    float zv[4] = { X0.z, X1.y, X2.x, X2.w };
    #pragma unroll 1
    for (int i = 0; i < 8; ++i) {
      float rx = rp[qh][i * 3 + 0];
      float ry = rp[qh][i * 3 + 1];
      float rz = rp[qh][i * 3 + 2];
      const u16* tp = tb + i * 8000;
      #pragma unroll
      for (int j = 0; j < 4; ++j) {
        Axis ax = axis_setup(rx - xv[j], 8);
        Axis ay = axis_setup(ry - yv[j], 80);
        Axis az = axis_setup(rz - zv[j], 800);
        float w00 = az.w0 * ay.w0, w01 = az.w0 * ay.w1;
        float w10 = az.w1 * ay.w0, w11 = az.w1 * ay.w1;
        U16x8 u;
        u.u = *(const uint4*)(tp + az.o0 + ay.o0 + ax.o0); DO_CORNER(u, w00 * ax.w0, j);
        u.u = *(const uint4*)(tp + az.o0 + ay.o0 + ax.o1); DO_CORNER(u, w00 * ax.w1, j);
        u.u = *(const uint4*)(tp + az.o0 + ay.o1 + ax.o0); DO_CORNER(u, w01 * ax.w0, j);
        u.u = *(const uint4*)(tp + az.o0 + ay.o1 + ax.o1); DO_CORNER(u, w01 * ax.w1, j);
        u.u = *(const uint4*)(tp + az.o1 + ay.o0 + ax.o0); DO_CORNER(u, w10 * ax.w0, j);
        u.u = *(const uint4*)(tp + az.o1 + ay.o0 + ax.o1); DO_CORNER(u, w10 * ax.w1, j);
        u.u = *(const uint4*)(tp + az.o1 + ay.o1 + ax.o0); DO_CORNER(u, w11 * ax.w0, j);
        u.u = *(const uint4*)(tp + az.o1 + ay.o1 + ax.o1); DO_CORNER(u, w11 * ax.w1, j);
      }
    }
  }

  // phase 3: softmax
  float mx[8];
  #pragma unroll
  for (int h = 0; h < 8; ++h) {
    float m = fmaxf(fmaxf(acc[h][0], acc[h][1]), fmaxf(acc[h][2], acc[h][3]));
    #pragma unroll
    for (int off = 32; off >= 1; off >>= 1) m = fmaxf(m, __shfl_xor(m, off, 64));
    mx[h] = m;
  }
  if (l == 0) {
    #pragma unroll
    for (int h = 0; h < 8; ++h) red[qh][h * 8 + wvl] = mx[h];
  }
  __syncthreads();   // tables dead after this point; un[] reusable as p
  #pragma unroll
  for (int h = 0; h < 8; ++h) {
    float4 r0 = *(const float4*)&red[qh][h * 8];
    float4 r1 = *(const float4*)&red[qh][h * 8 + 4];
    mx[h] = fmaxf(fmaxf(fmaxf(r0.x, r0.y), fmaxf(r0.z, r0.w)),
                  fmaxf(fmaxf(r1.x, r1.y), fmaxf(r1.z, r1.w)));
  }
  __syncthreads();
  float sm[8];
  #pragma unroll
  for (int h = 0; h < 8; ++h) {
    acc[h][0] = __expf(acc[h][0] - mx[h]);
    acc[h][1] = __expf(acc[h][1] - mx[h]);
    acc[h][2] = __expf(acc[h][2] - mx[h]);
    acc[h][3] = __expf(acc[h][3] - mx[h]);
    float s = (acc[h][0] + acc[h][1]) + (acc[h][2] + acc[h][3]);
    #pragma unroll
    for (int off = 32; off >= 1; off >>= 1) s += __shfl_xor(s, off, 64);
    sm[h] = s;
  }
  if (l == 0) {
    #pragma unroll
    for (int h = 0; h < 8; ++h) red[qh][h * 8 + wvl] = sm[h];
  }
  __syncthreads();
  // phase 3.5: normalize; p -> LDS; attn -> global directly (wave-contiguous float4)
  #pragma unroll
  for (int h = 0; h < 8; ++h) {
    float4 r0 = *(const float4*)&red[qh][h * 8];
    float4 r1 = *(const float4*)&red[qh][h * 8 + 4];
    float s = ((r0.x + r0.y) + (r0.z + r0.w)) + ((r1.x + r1.y) + (r1.z + r1.w));
    float inv = 1.f / s;
    float4 pv;
    pv.x = acc[h][0] * inv; pv.y = acc[h][1] * inv;
    pv.z = acc[h][2] * inv; pv.w = acc[h][3] * inv;
    *(float4*)&p[(qh * 8 + h) * 2048 + k0] = pv;
    *(float4*)&attn[((size_t)((b * 8 + h) * 256 + q)) * 2048 + k0] = pv;
  }
  __syncthreads();

  // phase 4: x = p @ v
  {
    int ch = wv >> 1, pqh = wv & 1;
    int ks2 = l >> 3, dq = l & 7;
    float a2[8][4] = {};
    const float* vbase = vp + ((size_t)(b * NK + ch * 256)) * 32 + dq * 4;
    const float* prow = p + pqh * 16384 + ch * 256;
    #pragma unroll 2
    for (int kk = 0; kk < 32; ++kk) {
      int ko = kk * 8 + ks2;
      float4 v4 = *(const float4*)&vbase[ko * 32];
      #pragma unroll
      for (int h = 0; h < 8; ++h) {
        float pvv = prow[h * 2048 + ko];
        a2[h][0] = fmaf(pvv, v4.x, a2[h][0]);
        a2[h][1] = fmaf(pvv, v4.y, a2[h][1]);
        a2[h][2] = fmaf(pvv, v4.z, a2[h][2]);
        a2[h][3] = fmaf(pvv, v4.w, a2[h][3]);
      }
    }
    #pragma unroll
    for (int off = 8; off <= 32; off <<= 1) {
      #pragma unroll
      for (int h = 0; h < 8; ++h) {
        a2[h][0] += __shfl_xor(a2[h][0], off, 64);
        a2[h][1] += __shfl_xor(a2[h][1], off, 64);
        a2[h][2] += __shfl_xor(a2[h][2], off, 64);
        a2[h][3] += __shfl_xor(a2[h][3], off, 64);
      }
    }
    if (ks2 == 0) {
      #pragma unroll
      for (int h = 0; h < 8; ++h) {
        float4 w4; w4.x = a2[h][0]; w4.y = a2[h][1]; w4.z = a2[h][2]; w4.w = a2[h][3];
        *(float4*)&red4[pqh][ch][h][dq * 4] = w4;
      }
    }
  }
  __syncthreads();
  if (t < 512) {
    int pqh = t >> 8, m = t & 255;
    int h = m >> 5, d = m & 31;
    float s = 0.f;
    #pragma unroll
    for (int ch = 0; ch < 8; ++ch) s += red4[pqh][ch][h][d];
    qrow[pqh][m] = s;
  }
  __syncthreads();

  // phase 5: out = x @ pw + pb
  {
    float* scratch = (float*)red4;
    int c = t & 255, half = (t >> 8) & 1, pqh = t >> 9;
    int m0 = half * 128;
    float a = 0.f;
    #pragma unroll 4
    for (int m = 0; m < 128; ++m) {
      a = fmaf(qrow[pqh][m0 + m], pw[(m0 + m) * 256 + c], a);
    }
    scratch[(pqh * 2 + half) * 256 + c] = a;
  }
  __syncthreads();
  if (t < 512) {
    float* scratch = (float*)red4;
    int pqh = t >> 8, c = t & 255;
    float v = scratch[(pqh * 2) * 256 + c] + scratch[(pqh * 2 + 1) * 256 + c] + pb[c];
    int qq = qc * 2 + pqh;
    out[(qq * BB + b) * 256 + c] = v;
  }
}

// ---------------- launch ----------------
extern "C" void kernel_launch(void* const* d_in, const int* in_sizes, int n_in,
                              void* d_out, int out_size, void* d_ws, size_t ws_size,
                              hipStream_t stream) {
  const float* query = (const float*)d_in[0];
  const float* key   = (const float*)d_in[1];
  const float* refp  = (const float*)d_in[2];
  // d_in[3] reference_angle: unused by reference
  const float* xyz   = (const float*)d_in[4];
  const float* qw    = (const float*)d_in[5];
  const float* qb    = (const float*)d_in[6];
  const float* kw    = (const float*)d_in[7];
  const float* kb    = (const float*)d_in[8];
  const float* vw    = (const float*)d_in[9];
  const float* vb    = (const float*)d_in[10];
  const float* pw    = (const float*)d_in[11];
  const float* pb    = (const float*)d_in[12];
  const float* w1    = (const float*)d_in[13];
  const float* b1    = (const float*)d_in[14];
  const float* w2    = (const float*)d_in[15];

  char* ws = (char*)d_ws;
  u16*   tb  = (u16*)(ws + TB_OFF);
  float* qp  = (float*)(ws + QP_OFF);
  float* kpT = (float*)(ws + KT_OFF);
  float* vp  = (float*)(ws + VP_OFF);
  float* out  = (float*)d_out;
  float* attn = out + 131072;  // second tuple output

  void* args[] = { (void*)&query, (void*)&key, (void*)&qw, (void*)&qb,
                   (void*)&kw, (void*)&kb, (void*)&vw, (void*)&vb,
                   (void*)&w1, (void*)&b1, (void*)&w2,
                   (void*)&xyz, (void*)&refp, (void*)&pw, (void*)&pb,
                   (void*)&tb, (void*)&qp, (void*)&kpT, (void*)&vp,
                   (void*)&attn, (void*)&out };
  hipLaunchCooperativeKernel((void*)k_all, dim3(256), dim3(1024), args, 0, stream);
}

// Round 8
// 185.432 us; speedup vs baseline: 1.3182x; 1.3182x over previous
//
#include <hip/hip_runtime.h>
#include <hip/hip_bf16.h>
#include <cstdint>

#define NQ 256
#define NK 2048
#define BB 2
#define SCALE 0.17677669529663687f  // 32^-0.5

// ws byte offsets (16B aligned)
#define TB_OFF 0u         // f16[64000]   tables [i][z][y][x][h]          128000 B
#define QP_OFF 128000u    // float[131072]  q-proj (B,nQ,256), pre-scaled 524288 B
#define KT_OFF 652288u    // float[131072]  k-proj transposed (B,32,nK)   524288 B
#define VP_OFF 1176576u   // float[131072]  v-proj (B,nK,32)              524288 B

typedef unsigned short u16;
typedef _Float16 h16;
union U16x8 { uint4 u; h16 h[8]; };

// ---------------- kernel 0: fused prep (tables + kv-proj + q-proj) ----------------
// blocks [0,256): kv-proj   [256,320): q-proj   [320,352): cpb tables (8 i x 4 cc)
__global__ __launch_bounds__(512) void k_prep(const float* __restrict__ query,
                                              const float* __restrict__ key,
                                              const float* __restrict__ qw,
                                              const float* __restrict__ qb,
                                              const float* __restrict__ kw,
                                              const float* __restrict__ kb,
                                              const float* __restrict__ vw,
                                              const float* __restrict__ vb,
                                              const float* __restrict__ w1g,
                                              const float* __restrict__ b1g,
                                              const float* __restrict__ w2g,
                                              u16* __restrict__ tb,
                                              float* __restrict__ qp,
                                              float* __restrict__ kpT,
                                              float* __restrict__ vp) {
  __shared__ __align__(16) char smraw[16 * 257 * 4];
  int bid = blockIdx.x, t = threadIdx.x;

  if (bid < 256) {
    // ---- kv-proj: kpT[b][d][k] (LDS-transposed), vp[b][k][d] (direct) ----
    float (*rows)[257] = (float(*)[257])smraw;
    int b = bid >> 7, kc = bid & 127;
    for (int idx = t; idx < 4096; idx += 512) {
      int r = idx >> 8, m = idx & 255;
      rows[r][m] = key[((kc * 16 + r) * BB + b) * 256 + m];
    }
    __syncthreads();
    int ks = t >> 5, d = t & 31;
    float a = kb[d], av = vb[d];
    #pragma unroll 4
    for (int m = 0; m < 256; ++m) {
      float rv = rows[ks][m];
      a  = fmaf(rv, kw[m * 32 + d], a);
      av = fmaf(rv, vw[m * 32 + d], av);
    }
    int k = kc * 16 + ks;
    vp[(b * NK + k) * 32 + d] = av;        // coalesced: d consecutive across lanes
    __syncthreads();                       // rows no longer needed
    float* f1 = (float*)smraw;             // 512 floats
    f1[d * 16 + ks] = a;
    __syncthreads();
    int dd = t >> 4, kk = t & 15;          // 512 threads cover 32x16
    kpT[(b * 32 + dd) * NK + kc * 16 + kk] = f1[dd * 16 + kk];
  } else if (bid < 320) {
    // ---- q-proj (pre-scaled): 8 rows per block ----
    float (*rows)[257] = (float(*)[257])smraw;
    int qg = bid - 256;  // 0..63, 8 global rows each
    for (int idx = t; idx < 2048; idx += 512) {
      int r = idx >> 8, m = idx & 255;
      int g = qg * 8 + r, b = g >> 8, q = g & 255;
      rows[r][m] = query[(q * BB + b) * 256 + m];
    }
    __syncthreads();
    int r = t >> 6, c0 = (t & 63) * 4;
    int g = qg * 8 + r;
    float4 acc = *(const float4*)&qb[c0];
    #pragma unroll 4
    for (int m = 0; m < 256; ++m) {
      float rv = rows[r][m];
      float4 w4 = *(const float4*)&qw[m * 256 + c0];
      acc.x = fmaf(rv, w4.x, acc.x); acc.y = fmaf(rv, w4.y, acc.y);
      acc.z = fmaf(rv, w4.z, acc.z); acc.w = fmaf(rv, w4.w, acc.w);
    }
    float4 o; o.x = acc.x * SCALE; o.y = acc.y * SCALE; o.z = acc.z * SCALE; o.w = acc.w * SCALE;
    *(float4*)&qp[g * 256 + c0] = o;
  } else {
    // ---- cpb tables (f16): 32 blocks = 8 i x 4 cc, 250 cells each ----
    float* w1 = (float*)smraw;          // 384
    float* b1 = w1 + 384;               // 128
    float* w2 = b1 + 128;               // 1024
    int ib = bid - 320;
    int i = ib >> 2, cc = ib & 3;
    for (int idx = t; idx < 384; idx += 512) w1[idx] = w1g[i * 384 + idx];
    if (t < 128) b1[t] = b1g[i * 128 + t];
    for (int idx = t; idx < 1024; idx += 512) w2[idx] = w2g[i * 1024 + idx];
    __syncthreads();
    if (t < 250) {
      int cell = cc * 250 + t;
      int z = cell / 100, y = (cell / 10) % 10, x = cell % 10;
      const float step = 8.0f / 9.0f;
      float cz = -4.f + z * step, cy = -4.f + y * step, cx = -4.f + x * step;
      float o0 = 0, o1 = 0, o2 = 0, o3 = 0, o4 = 0, o5 = 0, o6 = 0, o7 = 0;
      for (int d = 0; d < 128; ++d) {
        float h = fmaxf(fmaf(cz, w1[d], fmaf(cy, w1[128 + d], fmaf(cx, w1[256 + d], b1[d]))), 0.f);
        const float* w2r = &w2[d * 8];
        o0 = fmaf(h, w2r[0], o0); o1 = fmaf(h, w2r[1], o1);
        o2 = fmaf(h, w2r[2], o2); o3 = fmaf(h, w2r[3], o3);
        o4 = fmaf(h, w2r[4], o4); o5 = fmaf(h, w2r[5], o5);
        o6 = fmaf(h, w2r[6], o6); o7 = fmaf(h, w2r[7], o7);
      }
      U16x8 R;
      R.h[0] = (h16)o0; R.h[1] = (h16)o1; R.h[2] = (h16)o2; R.h[3] = (h16)o3;
      R.h[4] = (h16)o4; R.h[5] = (h16)o5; R.h[6] = (h16)o6; R.h[7] = (h16)o7;
      *(uint4*)&tb[i * 8000 + cell * 8] = R.u;
    }
  }
}

// ---------------- kernel 1: mega (qk + rpe + softmax + av + proj) ----------------
struct Axis { int o0, o1; float w0, w1; };

static __device__ __forceinline__ Axis axis_setup(float dv, int stride) {
  float g = copysignf(__log2f(fmaf(fabsf(dv), 512.f, 1.f)) * (1.f / 12.f), dv);
  float p = fmaf(g, 4.5f, 4.5f);
  float f = floorf(p);
  int i0 = (int)f;
  float w1v = p - f;
  float w0v = 1.f - w1v;
  Axis a;
  a.w0 = ((unsigned)i0 <= 9u) ? w0v : 0.f;
  a.w1 = ((unsigned)(i0 + 1) <= 9u) ? w1v : 0.f;
  int c0 = min(max(i0, 0), 9);
  int c1 = min(max(i0 + 1, 0), 9);
  a.o0 = c0 * stride;
  a.o1 = c1 * stride;
  return a;
}

// single-instruction f16*f32+f32 via v_fma_mix_f32 (f16 operand read in-register)
#define MIX2(A0, A1, U32, W) \
  asm("v_fma_mix_f32 %0, %1, %2, %0 op_sel:[0,0,0] op_sel_hi:[1,0,0]" : "+v"(A0) : "v"(U32), "v"(W)); \
  asm("v_fma_mix_f32 %0, %1, %2, %0 op_sel:[1,0,0] op_sel_hi:[1,0,0]" : "+v"(A1) : "v"(U32), "v"(W));

#define DO_CORNER(U, W, J) do { float ww = (W); \
  MIX2(acc[0][J], acc[1][J], (U).x, ww) \
  MIX2(acc[2][J], acc[3][J], (U).y, ww) \
  MIX2(acc[4][J], acc[5][J], (U).z, ww) \
  MIX2(acc[6][J], acc[7][J], (U).w, ww) } while (0)

__global__ __launch_bounds__(1024, 4) void k_mega(const u16* __restrict__ tbw,
                                                  const float* __restrict__ qp,
                                                  const float* __restrict__ kpT,
                                                  const float* __restrict__ xyz,
                                                  const float* __restrict__ refp,
                                                  const float* __restrict__ vp,
                                                  const float* __restrict__ pw,
                                                  const float* __restrict__ pb,
                                                  float* __restrict__ attn,
                                                  float* __restrict__ out) {
  // un: phase 1-2 = f16 tables (125 KB); phase 4 = p f32 [2][8][2048] (128 KB)
  __shared__ __align__(16) char un[131072];
  __shared__ __align__(16) float red4[2][8][8][32];  // 16 KB
  __shared__ __align__(16) float qrow[2][256];
  __shared__ __align__(16) float rp[2][24];
  __shared__ __align__(16) float red[2][64];
  u16* tb = (u16*)un;
  float* p = (float*)un;

  int t = threadIdx.x;
  int b = blockIdx.x >> 7, qc = blockIdx.x & 127;
  for (int idx = t; idx < 8000; idx += 1024)
    ((uint4*)tb)[idx] = ((const uint4*)tbw)[idx];
  if (t < 128) {
    int qh2 = t >> 6, c = t & 63;
    ((float4*)qrow[qh2])[c] = ((const float4*)(qp + (b * 256 + qc * 2 + qh2) * 256))[c];
  } else if (t < 140) {
    int idx = t - 128;
    int qh2 = idx / 6, c = idx % 6;
    ((float4*)rp[qh2])[c] = ((const float4*)(refp + (b * 256 + qc * 2 + qh2) * 24))[c];
  }
  __syncthreads();

  int wv = t >> 6, l = t & 63;
  int qh = wv >> 3, wvl = wv & 7;
  int q = qc * 2 + qh;
  int k0 = wvl * 256 + l * 4;
  float acc[8][4] = {};

  // phase 1: qk^T (q pre-scaled)
  const float* kT = kpT + b * (32 * NK);
  #pragma unroll 2
  for (int dq = 0; dq < 8; ++dq) {
    const float* kp0 = kT + (dq * 4) * NK + k0;
    float4 kv0 = *(const float4*)(kp0);
    float4 kv1 = *(const float4*)(kp0 + NK);
    float4 kv2 = *(const float4*)(kp0 + 2 * NK);
    float4 kv3 = *(const float4*)(kp0 + 3 * NK);
    #pragma unroll
    for (int h = 0; h < 8; ++h) {
      float4 qv = *(const float4*)&qrow[qh][h * 32 + dq * 4];
      acc[h][0] = fmaf(qv.x, kv0.x, fmaf(qv.y, kv1.x, fmaf(qv.z, kv2.x, fmaf(qv.w, kv3.x, acc[h][0]))));
      acc[h][1] = fmaf(qv.x, kv0.y, fmaf(qv.y, kv1.y, fmaf(qv.z, kv2.y, fmaf(qv.w, kv3.y, acc[h][1]))));
      acc[h][2] = fmaf(qv.x, kv0.z, fmaf(qv.y, kv1.z, fmaf(qv.z, kv2.z, fmaf(qv.w, kv3.z, acc[h][2]))));
      acc[h][3] = fmaf(qv.x, kv0.w, fmaf(qv.y, kv1.w, fmaf(qv.z, kv2.w, fmaf(qv.w, kv3.w, acc[h][3]))));
    }
  }

  // phase 2: rpe trilinear sampling via fma_mix
  {
    const float* xp = xyz + (size_t)(b * NK + k0) * 3;
    float4 X0 = *(const float4*)(xp);
    float4 X1 = *(const float4*)(xp + 4);
    float4 X2 = *(const float4*)(xp + 8);
    float xv[4] = { X0.x, X0.w, X1.z, X2.y };
    float yv[4] = { X0.y, X1.x, X1.w, X2.z };
    float zv[4] = { X0.z, X1.y, X2.x, X2.w };
    #pragma unroll 1
    for (int i = 0; i < 8; ++i) {
      float rx = rp[qh][i * 3 + 0];
      float ry = rp[qh][i * 3 + 1];
      float rz = rp[qh][i * 3 + 2];
      const u16* tp = tb + i * 8000;
      #pragma unroll
      for (int j = 0; j < 4; ++j) {
        Axis ax = axis_setup(rx - xv[j], 8);
        Axis ay = axis_setup(ry - yv[j], 80);
        Axis az = axis_setup(rz - zv[j], 800);
        // combined zy offsets (4 adds) then +x (8 adds)
        int o00 = az.o0 + ay.o0, o01 = az.o0 + ay.o1;
        int o10 = az.o1 + ay.o0, o11 = az.o1 + ay.o1;
        float w00 = az.w0 * ay.w0, w01 = az.w0 * ay.w1;
        float w10 = az.w1 * ay.w0, w11 = az.w1 * ay.w1;
        uint4 u;
        u = *(const uint4*)(tp + o00 + ax.o0); DO_CORNER(u, w00 * ax.w0, j);
        u = *(const uint4*)(tp + o00 + ax.o1); DO_CORNER(u, w00 * ax.w1, j);
        u = *(const uint4*)(tp + o01 + ax.o0); DO_CORNER(u, w01 * ax.w0, j);
        u = *(const uint4*)(tp + o01 + ax.o1); DO_CORNER(u, w01 * ax.w1, j);
        u = *(const uint4*)(tp + o10 + ax.o0); DO_CORNER(u, w10 * ax.w0, j);
        u = *(const uint4*)(tp + o10 + ax.o1); DO_CORNER(u, w10 * ax.w1, j);
        u = *(const uint4*)(tp + o11 + ax.o0); DO_CORNER(u, w11 * ax.w0, j);
        u = *(const uint4*)(tp + o11 + ax.o1); DO_CORNER(u, w11 * ax.w1, j);
      }
    }
  }

  // phase 3: softmax over k (2048) per head (8 waves per qh)
  float mx[8];
  #pragma unroll
  for (int h = 0; h < 8; ++h) {
    float m = fmaxf(fmaxf(acc[h][0], acc[h][1]), fmaxf(acc[h][2], acc[h][3]));
    #pragma unroll
    for (int off = 32; off >= 1; off >>= 1) m = fmaxf(m, __shfl_xor(m, off, 64));
    mx[h] = m;
  }
  if (l == 0) {
    #pragma unroll
    for (int h = 0; h < 8; ++h) red[qh][h * 8 + wvl] = mx[h];
  }
  __syncthreads();   // tables dead after this point; un[] reusable as p
  #pragma unroll
  for (int h = 0; h < 8; ++h) {
    float4 r0 = *(const float4*)&red[qh][h * 8];
    float4 r1 = *(const float4*)&red[qh][h * 8 + 4];
    mx[h] = fmaxf(fmaxf(fmaxf(r0.x, r0.y), fmaxf(r0.z, r0.w)),
                  fmaxf(fmaxf(r1.x, r1.y), fmaxf(r1.z, r1.w)));
  }
  __syncthreads();
  float sm[8];
  #pragma unroll
  for (int h = 0; h < 8; ++h) {
    acc[h][0] = __expf(acc[h][0] - mx[h]);
    acc[h][1] = __expf(acc[h][1] - mx[h]);
    acc[h][2] = __expf(acc[h][2] - mx[h]);
    acc[h][3] = __expf(acc[h][3] - mx[h]);
    float s = (acc[h][0] + acc[h][1]) + (acc[h][2] + acc[h][3]);
    #pragma unroll
    for (int off = 32; off >= 1; off >>= 1) s += __shfl_xor(s, off, 64);
    sm[h] = s;
  }
  if (l == 0) {
    #pragma unroll
    for (int h = 0; h < 8; ++h) red[qh][h * 8 + wvl] = sm[h];
  }
  __syncthreads();
  // phase 3.5: normalize; p -> LDS; attn -> global directly (wave-contiguous float4)
  #pragma unroll
  for (int h = 0; h < 8; ++h) {
    float4 r0 = *(const float4*)&red[qh][h * 8];
    float4 r1 = *(const float4*)&red[qh][h * 8 + 4];
    float s = ((r0.x + r0.y) + (r0.z + r0.w)) + ((r1.x + r1.y) + (r1.z + r1.w));
    float inv = 1.f / s;
    float4 pv;
    pv.x = acc[h][0] * inv; pv.y = acc[h][1] * inv;
    pv.z = acc[h][2] * inv; pv.w = acc[h][3] * inv;
    *(float4*)&p[(qh * 8 + h) * 2048 + k0] = pv;
    *(float4*)&attn[((size_t)((b * 8 + h) * 256 + q)) * 2048 + k0] = pv;
  }
  __syncthreads();

  // phase 4: x = p @ v
  {
    int ch = wv >> 1, pqh = wv & 1;
    int ks2 = l >> 3, dq = l & 7;
    float a2[8][4] = {};
    const float* vbase = vp + ((size_t)(b * NK + ch * 256)) * 32 + dq * 4;
    const float* prow = p + pqh * 16384 + ch * 256;
    #pragma unroll 2
    for (int kk = 0; kk < 32; ++kk) {
      int ko = kk * 8 + ks2;
      float4 v4 = *(const float4*)&vbase[ko * 32];
      #pragma unroll
      for (int h = 0; h < 8; ++h) {
        float pvv = prow[h * 2048 + ko];
        a2[h][0] = fmaf(pvv, v4.x, a2[h][0]);
        a2[h][1] = fmaf(pvv, v4.y, a2[h][1]);
        a2[h][2] = fmaf(pvv, v4.z, a2[h][2]);
        a2[h][3] = fmaf(pvv, v4.w, a2[h][3]);
      }
    }
    #pragma unroll
    for (int off = 8; off <= 32; off <<= 1) {
      #pragma unroll
      for (int h = 0; h < 8; ++h) {
        a2[h][0] += __shfl_xor(a2[h][0], off, 64);
        a2[h][1] += __shfl_xor(a2[h][1], off, 64);
        a2[h][2] += __shfl_xor(a2[h][2], off, 64);
        a2[h][3] += __shfl_xor(a2[h][3], off, 64);
      }
    }
    if (ks2 == 0) {
      #pragma unroll
      for (int h = 0; h < 8; ++h) {
        float4 w4; w4.x = a2[h][0]; w4.y = a2[h][1]; w4.z = a2[h][2]; w4.w = a2[h][3];
        *(float4*)&red4[pqh][ch][h][dq * 4] = w4;
      }
    }
  }
  __syncthreads();
  if (t < 512) {
    int pqh = t >> 8, m = t & 255;
    int h = m >> 5, d = m & 31;
    float s = 0.f;
    #pragma unroll
    for (int ch = 0; ch < 8; ++ch) s += red4[pqh][ch][h][d];
    qrow[pqh][m] = s;
  }
  __syncthreads();

  // phase 5: out = x @ pw + pb
  {
    float* scratch = (float*)red4;
    int c = t & 255, half = (t >> 8) & 1, pqh = t >> 9;
    int m0 = half * 128;
    float a = 0.f;
    #pragma unroll 4
    for (int m = 0; m < 128; ++m) {
      a = fmaf(qrow[pqh][m0 + m], pw[(m0 + m) * 256 + c], a);
    }
    scratch[(pqh * 2 + half) * 256 + c] = a;
  }
  __syncthreads();
  if (t < 512) {
    float* scratch = (float*)red4;
    int pqh = t >> 8, c = t & 255;
    float v = scratch[(pqh * 2) * 256 + c] + scratch[(pqh * 2 + 1) * 256 + c] + pb[c];
    int qq = qc * 2 + pqh;
    out[(qq * BB + b) * 256 + c] = v;
  }
}

// ---------------- launch ----------------
extern "C" void kernel_launch(void* const* d_in, const int* in_sizes, int n_in,
                              void* d_out, int out_size, void* d_ws, size_t ws_size,
                              hipStream_t stream) {
  const float* query = (const float*)d_in[0];
  const float* key   = (const float*)d_in[1];
  const float* refp  = (const float*)d_in[2];
  // d_in[3] reference_angle: unused by reference
  const float* xyz   = (const float*)d_in[4];
  const float* qw    = (const float*)d_in[5];
  const float* qb    = (const float*)d_in[6];
  const float* kw    = (const float*)d_in[7];
  const float* kb    = (const float*)d_in[8];
  const float* vw    = (const float*)d_in[9];
  const float* vb    = (const float*)d_in[10];
  const float* pw    = (const float*)d_in[11];
  const float* pb    = (const float*)d_in[12];
  const float* w1    = (const float*)d_in[13];
  const float* b1    = (const float*)d_in[14];
  const float* w2    = (const float*)d_in[15];

  char* ws = (char*)d_ws;
  u16*   tb  = (u16*)(ws + TB_OFF);
  float* qp  = (float*)(ws + QP_OFF);
  float* kpT = (float*)(ws + KT_OFF);
  float* vp  = (float*)(ws + VP_OFF);
  float* out  = (float*)d_out;
  float* attn = out + 131072;  // second tuple output

  hipLaunchKernelGGL(k_prep, dim3(352), dim3(512),  0, stream,
                     query, key, qw, qb, kw, kb, vw, vb, w1, b1, w2, tb, qp, kpT, vp);
  hipLaunchKernelGGL(k_mega, dim3(256), dim3(1024), 0, stream,
                     tb, qp, kpT, xyz, refp, vp, pw, pb, attn, out);
}